// Round 9
// baseline (329.734 us; speedup 1.0000x reference)
//
#include <hip/hip_runtime.h>

#define D 64
#define NB 256      // partition blocks for hist/scatter
#define BSHIFT 7    // bucket = 128 nodes
#define BUCK (1 << BSHIFT)
#define SLOTS 16    // u32 slots per node: 0=self, 1..14 edges, 15 chain/pad
#define NOVF 256    // sharded chain allocators (R2 lesson: single counter = 75us)
#define CPER 272    // chain blocks per shard
#define MAXCONT (NOVF * CPER)

typedef unsigned int u32;
typedef unsigned short u16;
typedef short bf8v __attribute__((ext_vector_type(8)));
typedef float f4v __attribute__((ext_vector_type(4)));
typedef u32 u32x2 __attribute__((ext_vector_type(2)));

__device__ __forceinline__ float bf_lo(u32 p) { return __uint_as_float(p << 16); }
__device__ __forceinline__ float bf_hi(u32 p) { return __uint_as_float(p & 0xffff0000u); }
__device__ __forceinline__ u32 bf_rne(float f) {
    u32 u = __float_as_uint(f);
    return (u + 0x7fffu + ((u >> 16) & 1u)) >> 16;
}

// ---------------- pass A: per-block bucket histogram (LDS atomics only) --------
// block 0 zeroes ovf shards + scan done-counter.
__global__ __launch_bounds__(256) void hist_k(const int* __restrict__ dst,
                                              int* __restrict__ histT, int E, int chunk,
                                              int nbuck, int* __restrict__ ovf,
                                              int* __restrict__ donecnt) {
    __shared__ int hh[1024];
    int t = threadIdx.x;
    if (blockIdx.x == 0) {
        if (t < NOVF) ovf[t] = 0;
        if (t == 0) *donecnt = 0;
    }
    for (int b = t; b < nbuck; b += 256) hh[b] = 0;
    __syncthreads();
    int start = blockIdx.x * chunk;
    int endi = min(E, start + chunk);
    for (int j = start + t; j < endi; j += 256) atomicAdd(&hh[dst[j] >> BSHIFT], 1);
    __syncthreads();
    for (int b = t; b < nbuck; b += 256) histT[b * NB + blockIdx.x] = hh[b];
}

// ---------------- grid scan for histT, final partial-scan folded in ----------
__global__ __launch_bounds__(1024) void gscan1_k(const int* __restrict__ in,
                                                 int* __restrict__ out,
                                                 int* __restrict__ partials,
                                                 int* __restrict__ blockoff,
                                                 int* __restrict__ donecnt, int M) {
    __shared__ int wsum[16];
    __shared__ int ps[256];
    __shared__ int lastflag;
    int t = threadIdx.x, wave = t >> 6, lane = t & 63;
    int i = blockIdx.x * 1024 + t;
    int v = (i < M) ? in[i] : 0;
    int x = v;
#pragma unroll
    for (int off = 1; off < 64; off <<= 1) {
        int y = __shfl_up(x, off, 64);
        if (lane >= off) x += y;
    }
    if (lane == 63) wsum[wave] = x;
    __syncthreads();
    if (wave == 0) {
        int s = (lane < 16) ? wsum[lane] : 0;
#pragma unroll
        for (int off = 1; off < 16; off <<= 1) {
            int y = __shfl_up(s, off, 64);
            if (lane >= off) s += y;
        }
        if (lane < 16) wsum[lane] = s;
    }
    __syncthreads();
    int woff = (wave > 0) ? wsum[wave - 1] : 0;
    if (i < M) out[i] = x + woff - v;
    if (t == 0) {
        partials[blockIdx.x] = wsum[15];
        __threadfence();
        int prev = atomicAdd(donecnt, 1);
        lastflag = (prev == (int)gridDim.x - 1);
    }
    __syncthreads();
    if (lastflag) {
        int nb = gridDim.x;
        if (t < 256) ps[t] = (t < nb) ? partials[t] : 0;
        __syncthreads();
        for (int off = 1; off < 256; off <<= 1) {
            int add = (t < 256 && t >= off) ? ps[t - off] : 0;
            __syncthreads();
            if (t < 256) ps[t] += add;
            __syncthreads();
        }
        if (t < 256) blockoff[t] = ps[t] - ((t < nb) ? partials[t] : 0);
    }
}

// seg(x) = histT[x] + blockoff2[x>>10]
__device__ __forceinline__ int seg_at(const int* __restrict__ histT,
                                      const int* __restrict__ blockoff2, int x) {
    return histT[x] + blockoff2[x >> 10];
}

// ---------------- pass B: scatter edges into bucket-sorted segments ----------
// Packed 4B entries: src in bits 0..23, dst&127 in bits 24..31.
__global__ __launch_bounds__(256) void bscat_k(const int* __restrict__ src,
                                               const int* __restrict__ dst,
                                               const int* __restrict__ histT,
                                               const int* __restrict__ blockoff2,
                                               u32* __restrict__ pairs, int E, int chunk,
                                               int nbuck) {
    __shared__ int sbase[1024];
    __shared__ int rank[1024];
    int t = threadIdx.x;
    for (int b = t; b < nbuck; b += 256) {
        sbase[b] = seg_at(histT, blockoff2, b * NB + blockIdx.x);
        rank[b] = 0;
    }
    __syncthreads();
    int start = blockIdx.x * chunk;
    int endi = min(E, start + chunk);
    for (int j = start + t; j < endi; j += 256) {
        int d = dst[j];
        int b = d >> BSHIFT;
        int pos = sbase[b] + atomicAdd(&rank[b], 1);
        pairs[pos] = (u32)src[j] | ((u32)(d & (BUCK - 1)) << 24);
    }
}

__device__ __forceinline__ void load_B(const float* __restrict__ W, bf8v Bf[2][4], int m,
                                       int quad) {
#pragma unroll
    for (int kc = 0; kc < 2; ++kc)
#pragma unroll
        for (int nb = 0; nb < 4; ++nb)
#pragma unroll
            for (int j = 0; j < 8; ++j)
                Bf[kc][nb][j] = (short)bf_rne(W[(32 * kc + 8 * quad + j) * D + m + 16 * nb]);
}

// ---------------- pass C: count + dinv + slot init + scatter + scaled gemm1 ---
// Weight-free slots (dinv folded into h'): slot = bare src index; pads = N
// (zero bf16 row). Slot 15 pad or chain 0x80000000|cb. After the scatter:
// layer-1 gemm h' = bf16(dinv*(x@W1)) for this bucket's rows.
// Block 0 zeroes h' row N (the pad target).
__global__ __launch_bounds__(256) void bfill3_k(
    const u32* __restrict__ pairs, const int* __restrict__ histT,
    const int* __restrict__ blockoff2, float* __restrict__ dinv,
    u32* __restrict__ pr, int* __restrict__ ovf,
    const float* __restrict__ xf, const float* __restrict__ W,
    u16* __restrict__ hout, int N, int nbuck, int E) {
    __shared__ int c[BUCK];
    __shared__ int lcur[BUCK];
    __shared__ int lcb[BUCK];
    __shared__ int lnb[BUCK];
    __shared__ float ldv[BUCK];
    int t = threadIdx.x;
    int b = blockIdx.x;
    int base = b << BSHIFT;
    int nvalid = min(BUCK, N - base);
    if (t < BUCK) c[t] = 0;
    if (b == 0 && t < 32) ((u32*)(hout + (size_t)N * D))[t] = 0u;  // zero row
    __syncthreads();
    int s0 = seg_at(histT, blockoff2, b * NB);
    int s1 = (b + 1 < nbuck) ? seg_at(histT, blockoff2, (b + 1) * NB) : E;
    for (int j = s0 + t; j < s1; j += 256) atomicAdd(&c[pairs[j] >> 24], 1);
    __syncthreads();
    if (t < BUCK) {
        int nblk = 0, cb = 0;
        int n = base + t;
        if (t < nvalid) {
            int cc = c[t];
            float di = rsqrtf((float)cc + 1.0f);
            ldv[t] = di;
            dinv[n] = di;
            nblk = (cc > 14) ? (cc / 15) : 0;
            if (nblk) {
                cb = (n & (NOVF - 1)) * CPER + atomicAdd(&ovf[n & (NOVF - 1)], nblk);
                for (int k = 0; k < nblk; ++k) {
                    int4* b4 = (int4*)(pr + ((size_t)N + (size_t)(cb + k)) * SLOTS);
                    int4 pad = make_int4(N, N, N, N);
                    b4[0] = pad; b4[1] = pad; b4[2] = pad;
                    b4[3] = make_int4(N, N, N,
                        (k < nblk - 1) ? (int)(0x80000000u | (u32)(cb + k + 1)) : N);
                }
            }
        }
        lcur[t] = 1;
        lcb[t] = cb;
        lnb[t] = nblk;
    }
    __syncthreads();
    // coalesced main slot-init: nvalid*4 int4s, contiguous
    int4* mb = (int4*)(pr + (size_t)base * SLOTS);
    for (int f = t; f < nvalid * 4; f += 256) {
        int nd = f >> 2, q = f & 3;
        int4 v = make_int4(N, N, N, N);
        if (q == 0) v.x = base + nd;                                     // self
        if (q == 3 && lnb[nd]) v.w = (int)(0x80000000u | (u32)lcb[nd]);  // chain
        mb[f] = v;
    }
    __syncthreads();
    // edge scatter (4B stores)
    for (int j = s0 + t; j < s1; j += 256) {
        u32 pe = pairs[j];
        u32 s = pe & 0x00FFFFFFu;
        int dloc = (int)(pe >> 24);
        int pos = atomicAdd(&lcur[dloc], 1);
        size_t w;
        if (pos < 15)
            w = (size_t)(base + dloc) * SLOTS + pos;
        else {
            int r = pos - 15;
            w = ((size_t)N + (size_t)(lcb[dloc] + r / 15)) * SLOTS + (r % 15);
        }
        pr[w] = s;
    }
    // layer-1 gemm for rows [base, base+BUCK), store scaled by ldv (dinv fold)
    int wave = t >> 6, lanei = t & 63, m = lanei & 15, quad = lanei >> 4;
    bf8v Bf[2][4];
    load_B(W, Bf, m, quad);
    for (int g = wave; g < BUCK / 16; g += 4) {
        int gbase = base + g * 16;
        if (gbase >= N) break;
        int r0 = gbase + m;
        if (r0 >= N) r0 = N - 1;
        const float* rp = xf + (size_t)r0 * D;
        float4 a0 = *(const float4*)(rp + quad * 8);
        float4 a1 = *(const float4*)(rp + quad * 8 + 4);
        float4 a2 = *(const float4*)(rp + 32 + quad * 8);
        float4 a3 = *(const float4*)(rp + 32 + quad * 8 + 4);
        bf8v Af0, Af1;
        Af0[0] = (short)bf_rne(a0.x); Af0[1] = (short)bf_rne(a0.y);
        Af0[2] = (short)bf_rne(a0.z); Af0[3] = (short)bf_rne(a0.w);
        Af0[4] = (short)bf_rne(a1.x); Af0[5] = (short)bf_rne(a1.y);
        Af0[6] = (short)bf_rne(a1.z); Af0[7] = (short)bf_rne(a1.w);
        Af1[0] = (short)bf_rne(a2.x); Af1[1] = (short)bf_rne(a2.y);
        Af1[2] = (short)bf_rne(a2.z); Af1[3] = (short)bf_rne(a2.w);
        Af1[4] = (short)bf_rne(a3.x); Af1[5] = (short)bf_rne(a3.y);
        Af1[6] = (short)bf_rne(a3.z); Af1[7] = (short)bf_rne(a3.w);
        f4v acc[4] = {{0.f, 0.f, 0.f, 0.f},
                      {0.f, 0.f, 0.f, 0.f},
                      {0.f, 0.f, 0.f, 0.f},
                      {0.f, 0.f, 0.f, 0.f}};
#pragma unroll
        for (int nb = 0; nb < 4; ++nb)
            acc[nb] = __builtin_amdgcn_mfma_f32_16x16x32_bf16(Af0, Bf[0][nb], acc[nb], 0, 0, 0);
#pragma unroll
        for (int nb = 0; nb < 4; ++nb)
            acc[nb] = __builtin_amdgcn_mfma_f32_16x16x32_bf16(Af1, Bf[1][nb], acc[nb], 0, 0, 0);
#pragma unroll
        for (int nb = 0; nb < 4; ++nb)
#pragma unroll
            for (int r = 0; r < 4; ++r) {
                int rowi = gbase + quad * 4 + r;
                if (rowi < N)
                    hout[(size_t)rowi * D + nb * 16 + m] =
                        (u16)bf_rne(acc[nb][r] * ldv[(g << 4) + quad * 4 + r]);
            }
    }
}

// ---------------- dense GEMM via MFMA (layer 2, bf16 input, unscaled) ---------
// Also zeroes g' row N (pad target for agg2).
__global__ __launch_bounds__(256) void gemm_k(const u32* __restrict__ hb,
                                              const float* __restrict__ W,
                                              u16* __restrict__ hout, int N) {
    int t = threadIdx.x;
    if (blockIdx.x == 0 && t < 32) ((u32*)(hout + (size_t)N * D))[t] = 0u;
    int lane = t & 63;
    int m = lane & 15;
    int quad = lane >> 4;
    bf8v Bf[2][4];
    load_B(W, Bf, m, quad);
    int ngroups = (N + 15) >> 4;
    int g = blockIdx.x * 4 + (t >> 6);
    int stride = gridDim.x * 4;
    for (; g < ngroups; g += stride) {
        int base = g * 16;
        int r0 = base + m;
        if (r0 >= N) r0 = N - 1;
        bf8v Af0 = *(const bf8v*)(hb + (size_t)r0 * 32 + quad * 4);
        bf8v Af1 = *(const bf8v*)(hb + (size_t)r0 * 32 + 16 + quad * 4);
        f4v acc[4] = {{0.f, 0.f, 0.f, 0.f},
                      {0.f, 0.f, 0.f, 0.f},
                      {0.f, 0.f, 0.f, 0.f},
                      {0.f, 0.f, 0.f, 0.f}};
#pragma unroll
        for (int nb = 0; nb < 4; ++nb)
            acc[nb] = __builtin_amdgcn_mfma_f32_16x16x32_bf16(Af0, Bf[0][nb], acc[nb], 0, 0, 0);
#pragma unroll
        for (int nb = 0; nb < 4; ++nb)
            acc[nb] = __builtin_amdgcn_mfma_f32_16x16x32_bf16(Af1, Bf[1][nb], acc[nb], 0, 0, 0);
#pragma unroll
        for (int nb = 0; nb < 4; ++nb)
#pragma unroll
            for (int r = 0; r < 4; ++r) {
                int rowi = base + quad * 4 + r;
                if (rowi < N) hout[(size_t)rowi * D + nb * 16 + m] = (u16)bf_rne(acc[nb][r]);
            }
    }
}

// ---------------- XCD-quartered gather agg -----------------------------------
// out = relu(dinv*(sum h'[slot]) + b). Feature dim split into 4 quarters of
// 16 features (32B row-segments). Quarter q runs ONLY on blocks with
// blockIdx%8 in {2q,2q+1} -> pinned to 2 XCDs [m09 round-robin], so each
// quarter's 3.2MB table slice is L2-RESIDENT there (attacks the line-request
// bound R8 exposed: bytes halved -> flat, so lines, not bytes, bind).
// Wave layout: lane = slot(0..15)*4 + p(0..3); ONE gather instr covers a
// node's 16 slots x 32B. Chain (slot15 sign) is wave-uniform. pr re-read per
// quarter via nontemporal loads (don't evict the table); outputs nt-stored.
__global__ __launch_bounds__(256) void aggq_k(const uint2* __restrict__ h2,
                                              const u32* __restrict__ pr,
                                              const float* __restrict__ dinv,
                                              const float* __restrict__ bias,
                                              float* __restrict__ out_f32,
                                              u16* __restrict__ out_b16, int N) {
    int t = threadIdx.x;
    int lane = t & 63;
    int r = lane >> 2;   // slot 0..15
    int p = lane & 3;    // 8B sub-chunk within the 32B quarter segment
    int xcd = blockIdx.x & 7;
    int q = xcd >> 1;    // feature quarter 0..3
    int w = (((int)blockIdx.x >> 3) * 2 + (xcd & 1)) * 4 + (t >> 6);
    int nw = gridDim.x;  // waves per quarter = (grid/8)*2*4
    if (w >= N) return;
    int fc = (q * 4 + p) * 4;  // first of this lane's 4 features
    float4 bq = *(const float4*)(bias + fc);
    u32 sraw = __builtin_nontemporal_load(&pr[(size_t)w * SLOTS + r]);
    for (int n = w; n < N; n += nw) {
        u32 cur = sraw;
        {   // prefetch next node's pr line
            int nn = n + nw;
            if (nn < N) sraw = __builtin_nontemporal_load(&pr[(size_t)nn * SLOTS + r]);
        }
        u32 idx = ((int)cur < 0) ? (u32)N : cur;
        uint2 g = h2[(size_t)idx * 16 + q * 4 + p];
        float v0 = bf_lo(g.x), v1 = bf_hi(g.x);
        float v2 = bf_lo(g.y), v3 = bf_hi(g.y);
        int flag = __shfl((int)cur, 63, 64);  // slot15 raw (lane 63: r=15)
        while (flag < 0) {  // wave-uniform chain walk (deg > 14)
            int cc = flag & 0x7FFFFFFF;
            u32 c2 = __builtin_nontemporal_load(
                &pr[((size_t)N + (size_t)cc) * SLOTS + r]);
            u32 idx2 = ((int)c2 < 0) ? (u32)N : c2;
            uint2 g2 = h2[(size_t)idx2 * 16 + q * 4 + p];
            v0 += bf_lo(g2.x); v1 += bf_hi(g2.x);
            v2 += bf_lo(g2.y); v3 += bf_hi(g2.y);
            flag = __shfl((int)c2, 63, 64);
        }
        // reduce over the 16 slot-groups (lane stride 4)
        v0 += __shfl_xor(v0, 4, 64);  v1 += __shfl_xor(v1, 4, 64);
        v2 += __shfl_xor(v2, 4, 64);  v3 += __shfl_xor(v3, 4, 64);
        v0 += __shfl_xor(v0, 8, 64);  v1 += __shfl_xor(v1, 8, 64);
        v2 += __shfl_xor(v2, 8, 64);  v3 += __shfl_xor(v3, 8, 64);
        v0 += __shfl_xor(v0, 16, 64); v1 += __shfl_xor(v1, 16, 64);
        v2 += __shfl_xor(v2, 16, 64); v3 += __shfl_xor(v3, 16, 64);
        v0 += __shfl_xor(v0, 32, 64); v1 += __shfl_xor(v1, 32, 64);
        v2 += __shfl_xor(v2, 32, 64); v3 += __shfl_xor(v3, 32, 64);
        float di = dinv[n];
        v0 = fmaxf(fmaf(di, v0, bq.x), 0.f);
        v1 = fmaxf(fmaf(di, v1, bq.y), 0.f);
        v2 = fmaxf(fmaf(di, v2, bq.z), 0.f);
        v3 = fmaxf(fmaf(di, v3, bq.w), 0.f);
        if (r == 0) {
            if (out_b16) {
                u32x2 o;
                o.x = bf_rne(di * v0) | (bf_rne(di * v1) << 16);
                o.y = bf_rne(di * v2) | (bf_rne(di * v3) << 16);
                __builtin_nontemporal_store(
                    o, (u32x2*)(out_b16 + (size_t)n * D + fc));
            } else {
                f4v o = {v0, v1, v2, v3};
                __builtin_nontemporal_store(
                    o, (f4v*)(out_f32 + (size_t)n * D + fc));
            }
        }
    }
}

// ---------------- launch ----------------

extern "C" void kernel_launch(void* const* d_in, const int* in_sizes, int n_in,
                              void* d_out, int out_size, void* d_ws, size_t ws_size,
                              hipStream_t stream) {
    const float* x  = (const float*)d_in[0];
    const int*   ei = (const int*)d_in[1];
    const float* W1 = (const float*)d_in[2];
    const float* b1 = (const float*)d_in[3];
    const float* W2 = (const float*)d_in[4];
    const float* b2 = (const float*)d_in[5];
    float* out = (float*)d_out;

    int N = in_sizes[0] / D;
    int E = in_sizes[1] / 2;
    const int* src = ei;
    const int* dst = ei + E;

    int nbuck = (N + BUCK - 1) >> BSHIFT;  // 782
    int chunk = (E + NB - 1) / NB;
    int M = nbuck * NB;                    // 200192

    char* ws = (char*)d_ws;
    size_t off = 0;
    auto align256 = [](size_t v) { return (v + 255) & ~(size_t)255; };
    float* dinv = (float*)(ws + off);  off += align256((size_t)N * 4);
    int* partials2 = (int*)(ws + off); off += 1024;
    int* blockoff2 = (int*)(ws + off); off += 1024;
    int* donecnt = (int*)(ws + off);   off += 256;
    int* ovf = (int*)(ws + off);       off += align256(NOVF * 4);
    int* histT = (int*)(ws + off);     off += align256((size_t)M * 4);
    u32* pairs = (u32*)(ws + off);     off += align256((size_t)E * 4);
    u32* pr = (u32*)(ws + off);        off += align256(((size_t)N + MAXCONT) * SLOTS * 4);
    u16* h = (u16*)(ws + off);         off += align256(((size_t)N + 1) * D * 2);
    u16* buf16 = (u16*)(ws + off);     off += align256((size_t)N * D * 2);

    dim3 b256(256);
    int nbG = (M + 1023) / 1024;  // 196
    int ngroups = (N + 15) / 16;
    int gemm_blocks = (ngroups + 3) / 4;

    hist_k<<<NB, b256, 0, stream>>>(dst, histT, E, chunk, nbuck, ovf, donecnt);
    gscan1_k<<<nbG, 1024, 0, stream>>>(histT, histT, partials2, blockoff2, donecnt, M);
    bscat_k<<<NB, b256, 0, stream>>>(src, dst, histT, blockoff2, pairs, E, chunk, nbuck);
    // count + dinv + slot init + scatter + h' = bf16(dinv*(x@W1)), per bucket
    bfill3_k<<<nbuck, b256, 0, stream>>>(pairs, histT, blockoff2, dinv, pr, ovf, x, W1, h,
                                         N, nbuck, E);
    // layer 1 agg (quartered): buf16 = bf16(dinv * relu(dinv*sum + b1))
    aggq_k<<<2048, b256, 0, stream>>>((const uint2*)h, pr, dinv, b1, nullptr, buf16, N);
    // layer 2: g' = buf16 @ W2 (pre-scaled input); out = relu(dinv*sum + b2)
    gemm_k<<<gemm_blocks, b256, 0, stream>>>((const u32*)buf16, W2, h, N);
    aggq_k<<<2048, b256, 0, stream>>>((const uint2*)h, pr, dinv, b2, out, nullptr, N);
}

// Round 10
// 195.921 us; speedup vs baseline: 1.6830x; 1.6830x over previous
//
#include <hip/hip_runtime.h>

#define D 64
#define NB 256      // partition blocks for hist/scatter
#define BSHIFT 7    // bucket = 128 nodes
#define BUCK (1 << BSHIFT)
#define SLOTS 16    // u32 slots per node: 0=self, 1..14 edges, 15 chain/pad
#define NOVF 256    // sharded chain allocators (R2 lesson: single counter = 75us)
#define CPER 272    // chain blocks per shard
#define MAXCONT (NOVF * CPER)

typedef unsigned int u32;
typedef unsigned short u16;
typedef short bf8v __attribute__((ext_vector_type(8)));
typedef float f4v __attribute__((ext_vector_type(4)));

__device__ __forceinline__ float bf_lo(u32 p) { return __uint_as_float(p << 16); }
__device__ __forceinline__ float bf_hi(u32 p) { return __uint_as_float(p & 0xffff0000u); }
__device__ __forceinline__ u32 bf_rne(float f) {
    u32 u = __float_as_uint(f);
    return (u + 0x7fffu + ((u >> 16) & 1u)) >> 16;
}

// ---------------- pass A: per-block bucket histogram (LDS atomics only) --------
// block 0 zeroes ovf shards + scan done-counter.
__global__ __launch_bounds__(256) void hist_k(const int* __restrict__ dst,
                                              int* __restrict__ histT, int E, int chunk,
                                              int nbuck, int* __restrict__ ovf,
                                              int* __restrict__ donecnt) {
    __shared__ int hh[1024];
    int t = threadIdx.x;
    if (blockIdx.x == 0) {
        if (t < NOVF) ovf[t] = 0;
        if (t == 0) *donecnt = 0;
    }
    for (int b = t; b < nbuck; b += 256) hh[b] = 0;
    __syncthreads();
    int start = blockIdx.x * chunk;
    int endi = min(E, start + chunk);
    for (int j = start + t; j < endi; j += 256) atomicAdd(&hh[dst[j] >> BSHIFT], 1);
    __syncthreads();
    for (int b = t; b < nbuck; b += 256) histT[b * NB + blockIdx.x] = hh[b];
}

// ---------------- grid scan for histT, final partial-scan folded in ----------
__global__ __launch_bounds__(1024) void gscan1_k(const int* __restrict__ in,
                                                 int* __restrict__ out,
                                                 int* __restrict__ partials,
                                                 int* __restrict__ blockoff,
                                                 int* __restrict__ donecnt, int M) {
    __shared__ int wsum[16];
    __shared__ int ps[256];
    __shared__ int lastflag;
    int t = threadIdx.x, wave = t >> 6, lane = t & 63;
    int i = blockIdx.x * 1024 + t;
    int v = (i < M) ? in[i] : 0;
    int x = v;
#pragma unroll
    for (int off = 1; off < 64; off <<= 1) {
        int y = __shfl_up(x, off, 64);
        if (lane >= off) x += y;
    }
    if (lane == 63) wsum[wave] = x;
    __syncthreads();
    if (wave == 0) {
        int s = (lane < 16) ? wsum[lane] : 0;
#pragma unroll
        for (int off = 1; off < 16; off <<= 1) {
            int y = __shfl_up(s, off, 64);
            if (lane >= off) s += y;
        }
        if (lane < 16) wsum[lane] = s;
    }
    __syncthreads();
    int woff = (wave > 0) ? wsum[wave - 1] : 0;
    if (i < M) out[i] = x + woff - v;
    if (t == 0) {
        partials[blockIdx.x] = wsum[15];
        __threadfence();
        int prev = atomicAdd(donecnt, 1);
        lastflag = (prev == (int)gridDim.x - 1);
    }
    __syncthreads();
    if (lastflag) {
        int nb = gridDim.x;
        if (t < 256) ps[t] = (t < nb) ? partials[t] : 0;
        __syncthreads();
        for (int off = 1; off < 256; off <<= 1) {
            int add = (t < 256 && t >= off) ? ps[t - off] : 0;
            __syncthreads();
            if (t < 256) ps[t] += add;
            __syncthreads();
        }
        if (t < 256) blockoff[t] = ps[t] - ((t < nb) ? partials[t] : 0);
    }
}

// seg(x) = histT[x] + blockoff2[x>>10]
__device__ __forceinline__ int seg_at(const int* __restrict__ histT,
                                      const int* __restrict__ blockoff2, int x) {
    return histT[x] + blockoff2[x >> 10];
}

// ---------------- pass B: scatter edges into bucket-sorted segments ----------
// Packed 4B entries: src in bits 0..23, dst&127 in bits 24..31.
__global__ __launch_bounds__(256) void bscat_k(const int* __restrict__ src,
                                               const int* __restrict__ dst,
                                               const int* __restrict__ histT,
                                               const int* __restrict__ blockoff2,
                                               u32* __restrict__ pairs, int E, int chunk,
                                               int nbuck) {
    __shared__ int sbase[1024];
    __shared__ int rank[1024];
    int t = threadIdx.x;
    for (int b = t; b < nbuck; b += 256) {
        sbase[b] = seg_at(histT, blockoff2, b * NB + blockIdx.x);
        rank[b] = 0;
    }
    __syncthreads();
    int start = blockIdx.x * chunk;
    int endi = min(E, start + chunk);
    for (int j = start + t; j < endi; j += 256) {
        int d = dst[j];
        int b = d >> BSHIFT;
        int pos = sbase[b] + atomicAdd(&rank[b], 1);
        pairs[pos] = (u32)src[j] | ((u32)(d & (BUCK - 1)) << 24);
    }
}

__device__ __forceinline__ void load_B(const float* __restrict__ W, bf8v Bf[2][4], int m,
                                       int quad) {
#pragma unroll
    for (int kc = 0; kc < 2; ++kc)
#pragma unroll
        for (int nb = 0; nb < 4; ++nb)
#pragma unroll
            for (int j = 0; j < 8; ++j)
                Bf[kc][nb][j] = (short)bf_rne(W[(32 * kc + 8 * quad + j) * D + m + 16 * nb]);
}

// ---------------- pass C: count + dinv + slot init + scatter + scaled gemm1 ---
// Weight-free slots (dinv folded into h'): slot = bare src index; pads = N
// (zero bf16 row). Slot 15 pad or chain 0x80000000|cb. After the scatter:
// layer-1 gemm h' = bf16(dinv*(x@W1)) for this bucket's rows.
// Block 0 zeroes h' row N (the pad target).
__global__ __launch_bounds__(256) void bfill3_k(
    const u32* __restrict__ pairs, const int* __restrict__ histT,
    const int* __restrict__ blockoff2, float* __restrict__ dinv,
    u32* __restrict__ pr, int* __restrict__ ovf,
    const float* __restrict__ xf, const float* __restrict__ W,
    u16* __restrict__ hout, int N, int nbuck, int E) {
    __shared__ int c[BUCK];
    __shared__ int lcur[BUCK];
    __shared__ int lcb[BUCK];
    __shared__ int lnb[BUCK];
    __shared__ float ldv[BUCK];
    int t = threadIdx.x;
    int b = blockIdx.x;
    int base = b << BSHIFT;
    int nvalid = min(BUCK, N - base);
    if (t < BUCK) c[t] = 0;
    if (b == 0 && t < 32) ((u32*)(hout + (size_t)N * D))[t] = 0u;  // zero row
    __syncthreads();
    int s0 = seg_at(histT, blockoff2, b * NB);
    int s1 = (b + 1 < nbuck) ? seg_at(histT, blockoff2, (b + 1) * NB) : E;
    for (int j = s0 + t; j < s1; j += 256) atomicAdd(&c[pairs[j] >> 24], 1);
    __syncthreads();
    if (t < BUCK) {
        int nblk = 0, cb = 0;
        int n = base + t;
        if (t < nvalid) {
            int cc = c[t];
            float di = rsqrtf((float)cc + 1.0f);
            ldv[t] = di;
            dinv[n] = di;
            nblk = (cc > 14) ? (cc / 15) : 0;
            if (nblk) {
                cb = (n & (NOVF - 1)) * CPER + atomicAdd(&ovf[n & (NOVF - 1)], nblk);
                for (int k = 0; k < nblk; ++k) {
                    int4* b4 = (int4*)(pr + ((size_t)N + (size_t)(cb + k)) * SLOTS);
                    int4 pad = make_int4(N, N, N, N);
                    b4[0] = pad; b4[1] = pad; b4[2] = pad;
                    b4[3] = make_int4(N, N, N,
                        (k < nblk - 1) ? (int)(0x80000000u | (u32)(cb + k + 1)) : N);
                }
            }
        }
        lcur[t] = 1;
        lcb[t] = cb;
        lnb[t] = nblk;
    }
    __syncthreads();
    // coalesced main slot-init: nvalid*4 int4s, contiguous
    int4* mb = (int4*)(pr + (size_t)base * SLOTS);
    for (int f = t; f < nvalid * 4; f += 256) {
        int nd = f >> 2, q = f & 3;
        int4 v = make_int4(N, N, N, N);
        if (q == 0) v.x = base + nd;                                     // self
        if (q == 3 && lnb[nd]) v.w = (int)(0x80000000u | (u32)lcb[nd]);  // chain
        mb[f] = v;
    }
    __syncthreads();
    // edge scatter (4B stores)
    for (int j = s0 + t; j < s1; j += 256) {
        u32 pe = pairs[j];
        u32 s = pe & 0x00FFFFFFu;
        int dloc = (int)(pe >> 24);
        int pos = atomicAdd(&lcur[dloc], 1);
        size_t w;
        if (pos < 15)
            w = (size_t)(base + dloc) * SLOTS + pos;
        else {
            int r = pos - 15;
            w = ((size_t)N + (size_t)(lcb[dloc] + r / 15)) * SLOTS + (r % 15);
        }
        pr[w] = s;
    }
    // layer-1 gemm for rows [base, base+BUCK), store scaled by ldv (dinv fold)
    int wave = t >> 6, lanei = t & 63, m = lanei & 15, quad = lanei >> 4;
    bf8v Bf[2][4];
    load_B(W, Bf, m, quad);
    for (int g = wave; g < BUCK / 16; g += 4) {
        int gbase = base + g * 16;
        if (gbase >= N) break;
        int r0 = gbase + m;
        if (r0 >= N) r0 = N - 1;
        const float* rp = xf + (size_t)r0 * D;
        float4 a0 = *(const float4*)(rp + quad * 8);
        float4 a1 = *(const float4*)(rp + quad * 8 + 4);
        float4 a2 = *(const float4*)(rp + 32 + quad * 8);
        float4 a3 = *(const float4*)(rp + 32 + quad * 8 + 4);
        bf8v Af0, Af1;
        Af0[0] = (short)bf_rne(a0.x); Af0[1] = (short)bf_rne(a0.y);
        Af0[2] = (short)bf_rne(a0.z); Af0[3] = (short)bf_rne(a0.w);
        Af0[4] = (short)bf_rne(a1.x); Af0[5] = (short)bf_rne(a1.y);
        Af0[6] = (short)bf_rne(a1.z); Af0[7] = (short)bf_rne(a1.w);
        Af1[0] = (short)bf_rne(a2.x); Af1[1] = (short)bf_rne(a2.y);
        Af1[2] = (short)bf_rne(a2.z); Af1[3] = (short)bf_rne(a2.w);
        Af1[4] = (short)bf_rne(a3.x); Af1[5] = (short)bf_rne(a3.y);
        Af1[6] = (short)bf_rne(a3.z); Af1[7] = (short)bf_rne(a3.w);
        f4v acc[4] = {{0.f, 0.f, 0.f, 0.f},
                      {0.f, 0.f, 0.f, 0.f},
                      {0.f, 0.f, 0.f, 0.f},
                      {0.f, 0.f, 0.f, 0.f}};
#pragma unroll
        for (int nb = 0; nb < 4; ++nb)
            acc[nb] = __builtin_amdgcn_mfma_f32_16x16x32_bf16(Af0, Bf[0][nb], acc[nb], 0, 0, 0);
#pragma unroll
        for (int nb = 0; nb < 4; ++nb)
            acc[nb] = __builtin_amdgcn_mfma_f32_16x16x32_bf16(Af1, Bf[1][nb], acc[nb], 0, 0, 0);
#pragma unroll
        for (int nb = 0; nb < 4; ++nb)
#pragma unroll
            for (int r = 0; r < 4; ++r) {
                int rowi = gbase + quad * 4 + r;
                if (rowi < N)
                    hout[(size_t)rowi * D + nb * 16 + m] =
                        (u16)bf_rne(acc[nb][r] * ldv[(g << 4) + quad * 4 + r]);
            }
    }
}

// ---------------- dense GEMM via MFMA (layer 2, bf16 input, unscaled) ---------
// Also zeroes g' row N (pad target for agg2).
__global__ __launch_bounds__(256) void gemm_k(const u32* __restrict__ hb,
                                              const float* __restrict__ W,
                                              u16* __restrict__ hout, int N) {
    int t = threadIdx.x;
    if (blockIdx.x == 0 && t < 32) ((u32*)(hout + (size_t)N * D))[t] = 0u;
    int lane = t & 63;
    int m = lane & 15;
    int quad = lane >> 4;
    bf8v Bf[2][4];
    load_B(W, Bf, m, quad);
    int ngroups = (N + 15) >> 4;
    int g = blockIdx.x * 4 + (t >> 6);
    int stride = gridDim.x * 4;
    for (; g < ngroups; g += stride) {
        int base = g * 16;
        int r0 = base + m;
        if (r0 >= N) r0 = N - 1;
        bf8v Af0 = *(const bf8v*)(hb + (size_t)r0 * 32 + quad * 4);
        bf8v Af1 = *(const bf8v*)(hb + (size_t)r0 * 32 + 16 + quad * 4);
        f4v acc[4] = {{0.f, 0.f, 0.f, 0.f},
                      {0.f, 0.f, 0.f, 0.f},
                      {0.f, 0.f, 0.f, 0.f},
                      {0.f, 0.f, 0.f, 0.f}};
#pragma unroll
        for (int nb = 0; nb < 4; ++nb)
            acc[nb] = __builtin_amdgcn_mfma_f32_16x16x32_bf16(Af0, Bf[0][nb], acc[nb], 0, 0, 0);
#pragma unroll
        for (int nb = 0; nb < 4; ++nb)
            acc[nb] = __builtin_amdgcn_mfma_f32_16x16x32_bf16(Af1, Bf[1][nb], acc[nb], 0, 0, 0);
#pragma unroll
        for (int nb = 0; nb < 4; ++nb)
#pragma unroll
            for (int r = 0; r < 4; ++r) {
                int rowi = base + quad * 4 + r;
                if (rowi < N) hout[(size_t)rowi * D + nb * 16 + m] = (u16)bf_rne(acc[nb][r]);
            }
    }
}

#define ADD8A(gt)                                                   \
    a0f += bf_lo((gt).x); a1f += bf_hi((gt).x);                     \
    a2f += bf_lo((gt).y); a3f += bf_hi((gt).y);                     \
    a4f += bf_lo((gt).z); a5f += bf_hi((gt).z);                     \
    a6f += bf_lo((gt).w); a7f += bf_hi((gt).w);
#define ADD8B(gt)                                                   \
    b0f += bf_lo((gt).x); b1f += bf_hi((gt).x);                     \
    b2f += bf_lo((gt).y); b3f += bf_hi((gt).y);                     \
    b4f += bf_lo((gt).z); b5f += bf_hi((gt).z);                     \
    b6f += bf_lo((gt).w); b7f += bf_hi((gt).w);

// ---------------- weight-free gather agg, DUAL-PAIR pipelined -----------------
// out = relu(dinv*(sum h'[slot]) + b). R7's 2-node/wave layout, but each wave
// processes TWO pair-iterations (i, i+nw) per loop body: all 8 gather instrs
// issue before either reduction -> 2x outstanding random line-requests per
// wave (attacks any latency-hiding shortfall; R8/R9 showed line REQUESTS are
// the binding resource). Chains handled after both FMA blocks. Final f32
// output stored nontemporally (don't evict g' during agg2).
__global__ __launch_bounds__(256) void aggu_k(const uint4* __restrict__ h4,
                                              const u32* __restrict__ pr,
                                              const float* __restrict__ dinv,
                                              const float* __restrict__ bias,
                                              float* __restrict__ out_f32,
                                              u16* __restrict__ out_b16, int N) {
    int t = threadIdx.x;
    int lane = t & 63;
    int p = lane & 7;
    int qh = (lane >> 3) & 3;
    int hh = lane >> 5;
    int fsel = (lane & 32) | 31;  // per-half broadcast src (lane 31 / lane 63)
    float4 ba = *(const float4*)(bias + 8 * p);
    float4 bb = *(const float4*)(bias + 8 * p + 4);
    int npair = (N + 1) >> 1;
    int wid = blockIdx.x * 4 + (t >> 6);
    int nw = gridDim.x * 4;
    if (wid >= npair) return;
    const int4* pr4 = (const int4*)pr;
    int nA0 = 2 * wid + hh;
    if (nA0 >= N) nA0 = N - 1;
    int4 pelA = pr4[(size_t)nA0 * 4 + qh];
    float pdvA = dinv[nA0];
    int iB0 = (wid + nw < npair) ? wid + nw : wid;
    int nB0 = 2 * iB0 + hh;
    if (nB0 >= N) nB0 = N - 1;
    int4 pelB = pr4[(size_t)nB0 * 4 + qh];
    float pdvB = dinv[nB0];
    for (int i = wid; i < npair; i += 2 * nw) {
        int iB = i + nw;
        bool vB = iB < npair;
        int nA = 2 * i + hh;
        if (nA >= N) nA = N - 1;
        int iBc = vB ? iB : i;
        int nB = 2 * iBc + hh;
        if (nB >= N) nB = N - 1;
        int4 elA = pelA;
        float diA = pdvA;
        int4 elB = pelB;
        float diB = pdvB;
        // issue BOTH pairs' gathers back-to-back (8 instrs in flight)
        u32 ax = ((int)elA.x < 0) ? (u32)N : (u32)elA.x;
        u32 ay = ((int)elA.y < 0) ? (u32)N : (u32)elA.y;
        u32 az = ((int)elA.z < 0) ? (u32)N : (u32)elA.z;
        u32 aw = ((int)elA.w < 0) ? (u32)N : (u32)elA.w;
        uint4 gA0 = h4[(size_t)ax * 8 + p];
        uint4 gA1 = h4[(size_t)ay * 8 + p];
        uint4 gA2 = h4[(size_t)az * 8 + p];
        uint4 gA3 = h4[(size_t)aw * 8 + p];
        u32 bx = ((int)elB.x < 0) ? (u32)N : (u32)elB.x;
        u32 by = ((int)elB.y < 0) ? (u32)N : (u32)elB.y;
        u32 bz = ((int)elB.z < 0) ? (u32)N : (u32)elB.z;
        u32 bw = ((int)elB.w < 0) ? (u32)N : (u32)elB.w;
        uint4 gB0 = h4[(size_t)bx * 8 + p];
        uint4 gB1 = h4[(size_t)by * 8 + p];
        uint4 gB2 = h4[(size_t)bz * 8 + p];
        uint4 gB3 = h4[(size_t)bw * 8 + p];
        {   // preload pairs i+2nw, i+3nw
            int jA = i + 2 * nw;
            int ja = (jA < npair) ? jA : i;
            int na = 2 * ja + hh;
            if (na >= N) na = N - 1;
            pelA = pr4[(size_t)na * 4 + qh];
            pdvA = dinv[na];
            int jB = i + 3 * nw;
            int jb = (jB < npair) ? jB : i;
            int nb2 = 2 * jb + hh;
            if (nb2 >= N) nb2 = N - 1;
            pelB = pr4[(size_t)nb2 * 4 + qh];
            pdvB = dinv[nb2];
        }
        float a0f = 0.f, a1f = 0.f, a2f = 0.f, a3f = 0.f;
        float a4f = 0.f, a5f = 0.f, a6f = 0.f, a7f = 0.f;
        float b0f = 0.f, b1f = 0.f, b2f = 0.f, b3f = 0.f;
        float b4f = 0.f, b5f = 0.f, b6f = 0.f, b7f = 0.f;
        ADD8A(gA0); ADD8A(gA1); ADD8A(gA2); ADD8A(gA3);
        ADD8B(gB0); ADD8B(gB1); ADD8B(gB2); ADD8B(gB3);
        // chain paths (deg > 14): half-uniform; idle half gathers zero row
        int slA = __shfl(elA.w, fsel, 64);
        while (__any(slA < 0)) {
            int4 e;
            if (slA < 0) {
                int cc = slA & 0x7FFFFFFF;
                e = pr4[((size_t)N + (size_t)cc) * 4 + qh];
            } else {
                e = make_int4(N, N, N, N);
            }
            u32 j0 = ((int)e.x < 0) ? (u32)N : (u32)e.x;
            u32 j1 = ((int)e.y < 0) ? (u32)N : (u32)e.y;
            u32 j2 = ((int)e.z < 0) ? (u32)N : (u32)e.z;
            u32 j3 = ((int)e.w < 0) ? (u32)N : (u32)e.w;
            gA0 = h4[(size_t)j0 * 8 + p];
            gA1 = h4[(size_t)j1 * 8 + p];
            gA2 = h4[(size_t)j2 * 8 + p];
            gA3 = h4[(size_t)j3 * 8 + p];
            ADD8A(gA0); ADD8A(gA1); ADD8A(gA2); ADD8A(gA3);
            slA = __shfl(e.w, fsel, 64);
        }
        int slB = __shfl(elB.w, fsel, 64);
        while (__any(slB < 0)) {
            int4 e;
            if (slB < 0) {
                int cc = slB & 0x7FFFFFFF;
                e = pr4[((size_t)N + (size_t)cc) * 4 + qh];
            } else {
                e = make_int4(N, N, N, N);
            }
            u32 j0 = ((int)e.x < 0) ? (u32)N : (u32)e.x;
            u32 j1 = ((int)e.y < 0) ? (u32)N : (u32)e.y;
            u32 j2 = ((int)e.z < 0) ? (u32)N : (u32)e.z;
            u32 j3 = ((int)e.w < 0) ? (u32)N : (u32)e.w;
            gB0 = h4[(size_t)j0 * 8 + p];
            gB1 = h4[(size_t)j1 * 8 + p];
            gB2 = h4[(size_t)j2 * 8 + p];
            gB3 = h4[(size_t)j3 * 8 + p];
            ADD8B(gB0); ADD8B(gB1); ADD8B(gB2); ADD8B(gB3);
            slB = __shfl(e.w, fsel, 64);
        }
        // reduce + finalize + store pair A
        a0f += __shfl_xor(a0f, 8, 64);  a1f += __shfl_xor(a1f, 8, 64);
        a2f += __shfl_xor(a2f, 8, 64);  a3f += __shfl_xor(a3f, 8, 64);
        a4f += __shfl_xor(a4f, 8, 64);  a5f += __shfl_xor(a5f, 8, 64);
        a6f += __shfl_xor(a6f, 8, 64);  a7f += __shfl_xor(a7f, 8, 64);
        a0f += __shfl_xor(a0f, 16, 64); a1f += __shfl_xor(a1f, 16, 64);
        a2f += __shfl_xor(a2f, 16, 64); a3f += __shfl_xor(a3f, 16, 64);
        a4f += __shfl_xor(a4f, 16, 64); a5f += __shfl_xor(a5f, 16, 64);
        a6f += __shfl_xor(a6f, 16, 64); a7f += __shfl_xor(a7f, 16, 64);
        a0f = fmaxf(fmaf(diA, a0f, ba.x), 0.f); a1f = fmaxf(fmaf(diA, a1f, ba.y), 0.f);
        a2f = fmaxf(fmaf(diA, a2f, ba.z), 0.f); a3f = fmaxf(fmaf(diA, a3f, ba.w), 0.f);
        a4f = fmaxf(fmaf(diA, a4f, bb.x), 0.f); a5f = fmaxf(fmaf(diA, a5f, bb.y), 0.f);
        a6f = fmaxf(fmaf(diA, a6f, bb.z), 0.f); a7f = fmaxf(fmaf(diA, a7f, bb.w), 0.f);
        if (qh == 0) {
            if (out_b16) {
                uint4 o;
                o.x = bf_rne(diA * a0f) | (bf_rne(diA * a1f) << 16);
                o.y = bf_rne(diA * a2f) | (bf_rne(diA * a3f) << 16);
                o.z = bf_rne(diA * a4f) | (bf_rne(diA * a5f) << 16);
                o.w = bf_rne(diA * a6f) | (bf_rne(diA * a7f) << 16);
                *(uint4*)(out_b16 + (size_t)nA * D + 8 * p) = o;
            } else {
                f4v o1 = {a0f, a1f, a2f, a3f};
                f4v o2 = {a4f, a5f, a6f, a7f};
                __builtin_nontemporal_store(o1, (f4v*)(out_f32 + (size_t)nA * D + 8 * p));
                __builtin_nontemporal_store(o2, (f4v*)(out_f32 + (size_t)nA * D + 8 * p + 4));
            }
        }
        // reduce + finalize + store pair B
        b0f += __shfl_xor(b0f, 8, 64);  b1f += __shfl_xor(b1f, 8, 64);
        b2f += __shfl_xor(b2f, 8, 64);  b3f += __shfl_xor(b3f, 8, 64);
        b4f += __shfl_xor(b4f, 8, 64);  b5f += __shfl_xor(b5f, 8, 64);
        b6f += __shfl_xor(b6f, 8, 64);  b7f += __shfl_xor(b7f, 8, 64);
        b0f += __shfl_xor(b0f, 16, 64); b1f += __shfl_xor(b1f, 16, 64);
        b2f += __shfl_xor(b2f, 16, 64); b3f += __shfl_xor(b3f, 16, 64);
        b4f += __shfl_xor(b4f, 16, 64); b5f += __shfl_xor(b5f, 16, 64);
        b6f += __shfl_xor(b6f, 16, 64); b7f += __shfl_xor(b7f, 16, 64);
        b0f = fmaxf(fmaf(diB, b0f, ba.x), 0.f); b1f = fmaxf(fmaf(diB, b1f, ba.y), 0.f);
        b2f = fmaxf(fmaf(diB, b2f, ba.z), 0.f); b3f = fmaxf(fmaf(diB, b3f, ba.w), 0.f);
        b4f = fmaxf(fmaf(diB, b4f, bb.x), 0.f); b5f = fmaxf(fmaf(diB, b5f, bb.y), 0.f);
        b6f = fmaxf(fmaf(diB, b6f, bb.z), 0.f); b7f = fmaxf(fmaf(diB, b7f, bb.w), 0.f);
        if (vB && qh == 0) {
            if (out_b16) {
                uint4 o;
                o.x = bf_rne(diB * b0f) | (bf_rne(diB * b1f) << 16);
                o.y = bf_rne(diB * b2f) | (bf_rne(diB * b3f) << 16);
                o.z = bf_rne(diB * b4f) | (bf_rne(diB * b5f) << 16);
                o.w = bf_rne(diB * b6f) | (bf_rne(diB * b7f) << 16);
                *(uint4*)(out_b16 + (size_t)nB * D + 8 * p) = o;
            } else {
                f4v o1 = {b0f, b1f, b2f, b3f};
                f4v o2 = {b4f, b5f, b6f, b7f};
                __builtin_nontemporal_store(o1, (f4v*)(out_f32 + (size_t)nB * D + 8 * p));
                __builtin_nontemporal_store(o2, (f4v*)(out_f32 + (size_t)nB * D + 8 * p + 4));
            }
        }
    }
}

// ---------------- launch ----------------

extern "C" void kernel_launch(void* const* d_in, const int* in_sizes, int n_in,
                              void* d_out, int out_size, void* d_ws, size_t ws_size,
                              hipStream_t stream) {
    const float* x  = (const float*)d_in[0];
    const int*   ei = (const int*)d_in[1];
    const float* W1 = (const float*)d_in[2];
    const float* b1 = (const float*)d_in[3];
    const float* W2 = (const float*)d_in[4];
    const float* b2 = (const float*)d_in[5];
    float* out = (float*)d_out;

    int N = in_sizes[0] / D;
    int E = in_sizes[1] / 2;
    const int* src = ei;
    const int* dst = ei + E;

    int nbuck = (N + BUCK - 1) >> BSHIFT;  // 782
    int chunk = (E + NB - 1) / NB;
    int M = nbuck * NB;                    // 200192

    char* ws = (char*)d_ws;
    size_t off = 0;
    auto align256 = [](size_t v) { return (v + 255) & ~(size_t)255; };
    float* dinv = (float*)(ws + off);  off += align256((size_t)N * 4);
    int* partials2 = (int*)(ws + off); off += 1024;
    int* blockoff2 = (int*)(ws + off); off += 1024;
    int* donecnt = (int*)(ws + off);   off += 256;
    int* ovf = (int*)(ws + off);       off += align256(NOVF * 4);
    int* histT = (int*)(ws + off);     off += align256((size_t)M * 4);
    u32* pairs = (u32*)(ws + off);     off += align256((size_t)E * 4);
    u32* pr = (u32*)(ws + off);        off += align256(((size_t)N + MAXCONT) * SLOTS * 4);
    u16* h = (u16*)(ws + off);         off += align256(((size_t)N + 1) * D * 2);
    u16* buf16 = (u16*)(ws + off);     off += align256((size_t)N * D * 2);

    dim3 b256(256);
    int nbG = (M + 1023) / 1024;  // 196
    int ngroups = (N + 15) / 16;
    int gemm_blocks = (ngroups + 3) / 4;

    hist_k<<<NB, b256, 0, stream>>>(dst, histT, E, chunk, nbuck, ovf, donecnt);
    gscan1_k<<<nbG, 1024, 0, stream>>>(histT, histT, partials2, blockoff2, donecnt, M);
    bscat_k<<<NB, b256, 0, stream>>>(src, dst, histT, blockoff2, pairs, E, chunk, nbuck);
    // count + dinv + slot init + scatter + h' = bf16(dinv*(x@W1)), per bucket
    bfill3_k<<<nbuck, b256, 0, stream>>>(pairs, histT, blockoff2, dinv, pr, ovf, x, W1, h,
                                         N, nbuck, E);
    // layer 1 agg: buf16 = bf16(dinv * relu(dinv*sum + b1))
    aggu_k<<<2560, b256, 0, stream>>>((const uint4*)h, pr, dinv, b1, nullptr, buf16, N);
    // layer 2: g' = buf16 @ W2 (pre-scaled input); out = relu(dinv*sum + b2)
    gemm_k<<<gemm_blocks, b256, 0, stream>>>((const u32*)buf16, W2, h, N);
    aggu_k<<<2560, b256, 0, stream>>>((const uint4*)h, pr, dinv, b2, out, nullptr, N);
}